// Round 1
// baseline (754.916 us; speedup 1.0000x reference)
//
#include <hip/hip_runtime.h>
#include <stdint.h>

typedef unsigned short u16;
typedef u16 us8 __attribute__((ext_vector_type(8)));
typedef __bf16 bf16x8 __attribute__((ext_vector_type(8)));
typedef float f32x4 __attribute__((ext_vector_type(4)));

#define BB 16
#define TT 2048
#define HH 1024
#define MM 32768   // B*T
#define NN 3072    // H + 2H
#define KK 1024

__device__ __forceinline__ float b2f(u16 u) {
    union { uint32_t i; float f; } v; v.i = ((uint32_t)u) << 16; return v.f;
}
__device__ __forceinline__ u16 f2b(float f) {
    union { uint32_t i; float f; } v; v.f = f;
    uint32_t r = v.i + 0x7fffu + ((v.i >> 16) & 1u);
    return (u16)(r >> 16);
}
__device__ __forceinline__ float sigm(float z) {
    return 1.f / (1.f + __expf(-z));
}

// ---- K0a: x fp32 -> bf16 -------------------------------------------------
__global__ __launch_bounds__(256) void k_cvt_x(const float* __restrict__ x,
                                               u16* __restrict__ o) {
    int i = (blockIdx.x * 256 + threadIdx.x) * 8;
    float4 a = *(const float4*)(x + i);
    float4 b = *(const float4*)(x + i + 4);
    us8 r;
    r[0] = f2b(a.x); r[1] = f2b(a.y); r[2] = f2b(a.z); r[3] = f2b(a.w);
    r[4] = f2b(b.x); r[5] = f2b(b.y); r[6] = f2b(b.z); r[7] = f2b(b.w);
    *(us8*)(o + i) = r;
}

// ---- K0b: [W_lt; W_g] fp32 -> bf16 (3072 x 1024) -------------------------
__global__ __launch_bounds__(256) void k_cvt_w(const float* __restrict__ wlt,
                                               const float* __restrict__ wg,
                                               u16* __restrict__ o) {
    int i = (blockIdx.x * 256 + threadIdx.x) * 8;
    const float* s = (i < 1024 * 1024) ? (wlt + i) : (wg + (i - 1024 * 1024));
    float4 a = *(const float4*)(s);
    float4 b = *(const float4*)(s + 4);
    us8 r;
    r[0] = f2b(a.x); r[1] = f2b(a.y); r[2] = f2b(a.z); r[3] = f2b(a.w);
    r[4] = f2b(b.x); r[5] = f2b(b.y); r[6] = f2b(b.z); r[7] = f2b(b.w);
    *(us8*)(o + i) = r;
}

// ---- K1: Y[32768,3072] = Xb[32768,1024] @ Wb[3072,1024]^T  (bf16 MFMA) ---
// 128x128 tile, 256 threads = 4 waves in 2x2, each wave 4x4 of 16x16x32.
__global__ __launch_bounds__(256) void k_gemm(const u16* __restrict__ A,
                                              const u16* __restrict__ W,
                                              u16* __restrict__ Y) {
    __shared__ u16 As[128 * 32];
    __shared__ u16 Bs[128 * 32];
    const int tid = threadIdx.x;
    const int lane = tid & 63;
    const int q = lane >> 4;       // quad 0..3
    const int l16 = lane & 15;
    const int w = tid >> 6;
    const int wm = (w >> 1) * 64, wn = (w & 1) * 64;
    const int bx = blockIdx.x, by = blockIdx.y;

    // staging: 512 x 16B segments per (A,B) tile pair; 2 segs each per thread
    const int s0 = tid, s1 = tid + 256;
    const int r0 = s0 >> 2, c0 = (s0 & 3) * 8;
    const int r1 = s1 >> 2, c1 = (s1 & 3) * 8;
    const u16* a0 = A + (by * 128 + r0) * KK + c0;
    const u16* a1 = A + (by * 128 + r1) * KK + c1;
    const u16* w0 = W + (bx * 128 + r0) * KK + c0;
    const u16* w1 = W + (bx * 128 + r1) * KK + c1;
    // XOR-swizzled LDS segment index (breaks 8-way bank conflict on frag reads)
    const int d0 = r0 * 4 + ((s0 & 3) ^ (r0 & 3));
    const int d1 = r1 * 4 + ((s1 & 3) ^ (r1 & 3));

    f32x4 zero = {0.f, 0.f, 0.f, 0.f};
    f32x4 acc[4][4];
#pragma unroll
    for (int i = 0; i < 4; i++)
#pragma unroll
        for (int j = 0; j < 4; j++) acc[i][j] = zero;

    for (int k0 = 0; k0 < KK; k0 += 32) {
        uint4 va0 = *(const uint4*)(a0 + k0);
        uint4 va1 = *(const uint4*)(a1 + k0);
        uint4 vb0 = *(const uint4*)(w0 + k0);
        uint4 vb1 = *(const uint4*)(w1 + k0);
        __syncthreads();
        ((uint4*)As)[d0] = va0;
        ((uint4*)As)[d1] = va1;
        ((uint4*)Bs)[d0] = vb0;
        ((uint4*)Bs)[d1] = vb1;
        __syncthreads();
        bf16x8 af[4], bv[4];
#pragma unroll
        for (int i = 0; i < 4; i++) {
            int r = wm + i * 16 + l16;
            af[i] = *(const bf16x8*)&As[(r * 4 + (q ^ (r & 3))) * 8];
        }
#pragma unroll
        for (int j = 0; j < 4; j++) {
            int r = wn + j * 16 + l16;
            bv[j] = *(const bf16x8*)&Bs[(r * 4 + (q ^ (r & 3))) * 8];
        }
#pragma unroll
        for (int i = 0; i < 4; i++)
#pragma unroll
            for (int j = 0; j < 4; j++)
                acc[i][j] = __builtin_amdgcn_mfma_f32_16x16x32_bf16(
                    af[i], bv[j], acc[i][j], 0, 0, 0);
    }

    // epilogue: C/D layout col=lane&15, row=quad*4+reg
#pragma unroll
    for (int i = 0; i < 4; i++) {
#pragma unroll
        for (int rg = 0; rg < 4; rg++) {
            int row = by * 128 + wm + i * 16 + q * 4 + rg;
            u16* yp = Y + (size_t)row * NN + bx * 128 + wn + l16;
#pragma unroll
            for (int j = 0; j < 4; j++) yp[j * 16] = f2b(acc[i][j][rg]);
        }
    }
}

// ---- K2: rowwise LN(2048)+sigmoid -> f, r; nd=(1-f)*x_tilde --------------
__global__ __launch_bounds__(256) void k_lnsig(const u16* __restrict__ Y,
                                               const float* __restrict__ bg,
                                               const float* __restrict__ gg,
                                               const float* __restrict__ bt,
                                               u16* __restrict__ F,
                                               u16* __restrict__ R,
                                               u16* __restrict__ ND) {
    const int row = blockIdx.x;
    const int t = threadIdx.x;
    const u16* yr = Y + (size_t)row * 3072;
    us8 gv = *(const us8*)(yr + 1024 + t * 8);
    float z[8];
    float s = 0.f, s2 = 0.f;
#pragma unroll
    for (int k = 0; k < 8; k++) {
        z[k] = b2f(gv[k]) + bg[t * 8 + k];
        s += z[k];
        s2 += z[k] * z[k];
    }
#pragma unroll
    for (int m = 1; m < 64; m <<= 1) {
        s += __shfl_xor(s, m);
        s2 += __shfl_xor(s2, m);
    }
    __shared__ float red[8];
    if ((t & 63) == 0) { red[t >> 6] = s; red[(t >> 6) + 4] = s2; }
    __syncthreads();
    s = red[0] + red[1] + red[2] + red[3];
    s2 = red[4] + red[5] + red[6] + red[7];
    const float mu = s * (1.f / 2048.f);
    const float inv = rsqrtf(s2 * (1.f / 2048.f) - mu * mu + 1e-5f);
    float gate[8];
#pragma unroll
    for (int k = 0; k < 8; k++)
        gate[k] = sigm((z[k] - mu) * inv * gg[t * 8 + k] + bt[t * 8 + k]);
    if (t < 128) {  // f-region, cols 0..1023 of gate
        us8 xt = *(const us8*)(yr + t * 8);
        us8 fo, no;
#pragma unroll
        for (int k = 0; k < 8; k++) {
            fo[k] = f2b(gate[k]);
            no[k] = f2b((1.f - gate[k]) * b2f(xt[k]));
        }
        *(us8*)(F + (size_t)row * 1024 + t * 8) = fo;
        *(us8*)(ND + (size_t)row * 1024 + t * 8) = no;
    } else {  // r-region
        us8 ro;
#pragma unroll
        for (int k = 0; k < 8; k++) ro[k] = f2b(gate[k]);
        *(us8*)(R + (size_t)row * 1024 + (t - 128) * 8) = ro;
    }
}

// ---- K3: scan pass 1 — per-(b,h,chunk) aggregates (F=prod f, N=local) ----
// chunk length 64, 32 chunks, 524288 threads
__global__ __launch_bounds__(256) void k_scan1(const u16* __restrict__ F,
                                               const u16* __restrict__ ND,
                                               float2* __restrict__ agg) {
    int u = blockIdx.x * 256 + threadIdx.x;
    int h = u & 1023;
    int chunk = (u >> 10) & 31;
    int b = u >> 15;
    int base = (b * 2048 + chunk * 64) * 1024 + h;
    float Fp = 1.f, Np = 0.f;
#pragma unroll 4
    for (int i = 0; i < 64; i++) {
        float f = b2f(F[base + i * 1024]);
        float n = b2f(ND[base + i * 1024]);
        Np = fmaf(f, Np, n);
        Fp *= f;
    }
    agg[(b * 1024 + h) * 32 + chunk] = make_float2(Fp, Np);
}

// ---- K4: scan over chunk aggregates -> per-chunk prefix P ----------------
__global__ __launch_bounds__(256) void k_scan2(const float2* __restrict__ agg,
                                               const float* __restrict__ c0,
                                               float* __restrict__ P) {
    int u = blockIdx.x * 256 + threadIdx.x;  // (b*1024+h), 16384 total
    float c = c0[u];
    const float2* a = agg + (size_t)u * 32;
    float* p = P + (size_t)u * 32;
#pragma unroll 4
    for (int k = 0; k < 32; k++) {
        p[k] = c;
        float2 fn = a[k];
        c = fmaf(fn.x, c, fn.y);
    }
}

// ---- K5: scan pass 2 — apply with prefix, emit all_c (bf16) + c_final ----
__global__ __launch_bounds__(256) void k_scan3(const u16* __restrict__ F,
                                               const u16* __restrict__ ND,
                                               const float* __restrict__ P,
                                               u16* __restrict__ C,
                                               float* __restrict__ cfin) {
    int u = blockIdx.x * 256 + threadIdx.x;
    int h = u & 1023;
    int chunk = (u >> 10) & 31;
    int b = u >> 15;
    int base = (b * 2048 + chunk * 64) * 1024 + h;
    float c = P[(b * 1024 + h) * 32 + chunk];
#pragma unroll 4
    for (int i = 0; i < 64; i++) {
        float f = b2f(F[base + i * 1024]);
        float n = b2f(ND[base + i * 1024]);
        c = fmaf(f, c, n);
        C[base + i * 1024] = f2b(c);
    }
    if (chunk == 31) cfin[b * 1024 + h] = c;
}

// ---- K6: h = r*sigmoid(LN_h(c)) + (1-r)*x  (one wave per row) ------------
__global__ __launch_bounds__(256) void k_final(const u16* __restrict__ C,
                                               const u16* __restrict__ R,
                                               const float* __restrict__ x,
                                               const float* __restrict__ ga,
                                               const float* __restrict__ ba,
                                               float* __restrict__ Ho) {
    const int w = threadIdx.x >> 6, lane = threadIdx.x & 63;
    const int row = blockIdx.x * 4 + w;
    const int col = lane * 16;
    const u16* cp = C + (size_t)row * 1024 + col;
    us8 cv0 = *(const us8*)cp;
    us8 cv1 = *(const us8*)(cp + 8);
    float c[16];
    float s = 0.f, s2 = 0.f;
#pragma unroll
    for (int k = 0; k < 8; k++) { c[k] = b2f(cv0[k]); c[8 + k] = b2f(cv1[k]); }
#pragma unroll
    for (int k = 0; k < 16; k++) { s += c[k]; s2 += c[k] * c[k]; }
#pragma unroll
    for (int m = 1; m < 64; m <<= 1) {
        s += __shfl_xor(s, m);
        s2 += __shfl_xor(s2, m);
    }
    const float mu = s * (1.f / 1024.f);
    const float inv = rsqrtf(s2 * (1.f / 1024.f) - mu * mu + 1e-5f);
    const u16* rp = R + (size_t)row * 1024 + col;
    us8 rv0 = *(const us8*)rp;
    us8 rv1 = *(const us8*)(rp + 8);
    const float* xp = x + (size_t)row * 1024 + col;
    float xv[16];
    *(float4*)&xv[0]  = *(const float4*)(xp);
    *(float4*)&xv[4]  = *(const float4*)(xp + 4);
    *(float4*)&xv[8]  = *(const float4*)(xp + 8);
    *(float4*)&xv[12] = *(const float4*)(xp + 12);
    float ho[16];
#pragma unroll
    for (int k = 0; k < 16; k++) {
        float sg = sigm((c[k] - mu) * inv * ga[col + k] + ba[col + k]);
        float rr = b2f(k < 8 ? rv0[k] : rv1[k - 8]);
        ho[k] = rr * sg + (1.f - rr) * xv[k];
    }
    float* op = Ho + (size_t)row * 1024 + col;
    *(float4*)(op)      = *(float4*)&ho[0];
    *(float4*)(op + 4)  = *(float4*)&ho[4];
    *(float4*)(op + 8)  = *(float4*)&ho[8];
    *(float4*)(op + 12) = *(float4*)&ho[12];
}

extern "C" void kernel_launch(void* const* d_in, const int* in_sizes, int n_in,
                              void* d_out, int out_size, void* d_ws, size_t ws_size,
                              hipStream_t stream) {
    const float* x   = (const float*)d_in[0];
    const float* c0  = (const float*)d_in[1];
    const float* wlt = (const float*)d_in[2];
    const float* wg  = (const float*)d_in[3];
    const float* bg  = (const float*)d_in[4];
    const float* gg  = (const float*)d_in[5];
    const float* btg = (const float*)d_in[6];
    const float* ga  = (const float*)d_in[7];
    const float* ba  = (const float*)d_in[8];
    float* out = (float*)d_out;

    char* ws = (char*)d_ws;
    u16* xb    = (u16*)(ws);                      // 67,108,864 B
    u16* wb    = (u16*)(ws + 67108864);           //  6,291,456 B
    u16* y     = (u16*)(ws + 73400320);           // 201,326,592 B
    u16* F     = (u16*)(ws + 274726912);          // 67,108,864 B
    u16* R     = (u16*)(ws + 341835776);          // 67,108,864 B
    u16* ND    = (u16*)(ws + 408944640);          // 67,108,864 B
    float2* agg = (float2*)(ws + 476053504);      //  4,194,304 B
    float* P   = (float*)(ws + 480247808);        //  2,097,152 B
    u16* C     = y;  // y dead after k_lnsig; reuse for all_c (needs 67 MB)

    k_cvt_x<<<16384, 256, 0, stream>>>(x, xb);
    k_cvt_w<<<1536, 256, 0, stream>>>(wlt, wg, wb);
    k_gemm<<<dim3(24, 256), 256, 0, stream>>>(xb, wb, y);
    k_lnsig<<<32768, 256, 0, stream>>>(y, bg, gg, btg, F, R, ND);
    k_scan1<<<2048, 256, 0, stream>>>(F, ND, agg);
    k_scan2<<<64, 256, 0, stream>>>(agg, c0, P);
    k_scan3<<<2048, 256, 0, stream>>>(F, ND, P, C, out + (size_t)33554432);
    k_final<<<8192, 256, 0, stream>>>(C, R, x, ga, ba, out);
}

// Round 2
// 712.373 us; speedup vs baseline: 1.0597x; 1.0597x over previous
//
#include <hip/hip_runtime.h>
#include <stdint.h>

typedef unsigned short u16;
typedef u16 us8 __attribute__((ext_vector_type(8)));
typedef uint32_t u32x8 __attribute__((ext_vector_type(8)));
typedef __bf16 bf16x8 __attribute__((ext_vector_type(8)));
typedef float f32x4 __attribute__((ext_vector_type(4)));

#define BB 16
#define TT 2048
#define HH 1024
#define MM 32768   // B*T
#define NN 3072    // H + 2H
#define KK 1024

__device__ __forceinline__ float b2f(u16 u) {
    union { uint32_t i; float f; } v; v.i = ((uint32_t)u) << 16; return v.f;
}
__device__ __forceinline__ u16 f2b(float f) {
    union { uint32_t i; float f; } v; v.f = f;
    uint32_t r = v.i + 0x7fffu + ((v.i >> 16) & 1u);
    return (u16)(r >> 16);
}
__device__ __forceinline__ float sigm(float z) {
    return 1.f / (1.f + __expf(-z));
}
__device__ __forceinline__ void load_lds16(const u16* g, u16* l) {
    __builtin_amdgcn_global_load_lds(
        (const __attribute__((address_space(1))) void*)g,
        (__attribute__((address_space(3))) void*)l, 16, 0, 0);
}

// ---- K0: x fp32 -> bf16, [W_lt;W_g] fp32 -> bf16 (merged) ----------------
__global__ __launch_bounds__(256) void k_cvt(const float* __restrict__ x,
                                             const float* __restrict__ wlt,
                                             const float* __restrict__ wg,
                                             u16* __restrict__ xb,
                                             u16* __restrict__ wb) {
    long i = (long)(blockIdx.x * 256 + threadIdx.x) * 8;
    const float* s;
    u16* o;
    if (i < 33554432L) { s = x + i; o = xb + i; }
    else {
        long j = i - 33554432L;
        s = (j < 1048576L) ? (wlt + j) : (wg + (j - 1048576L));
        o = wb + j;
    }
    float4 a = *(const float4*)(s);
    float4 b = *(const float4*)(s + 4);
    us8 r;
    r[0] = f2b(a.x); r[1] = f2b(a.y); r[2] = f2b(a.z); r[3] = f2b(a.w);
    r[4] = f2b(b.x); r[5] = f2b(b.y); r[6] = f2b(b.z); r[7] = f2b(b.w);
    *(us8*)o = r;
}

// ---- K1: Y[32768,3072] = Xb @ Wb^T  (bf16 MFMA, m97-style staging) -------
// 128x128 tile, 256 threads = 4 waves (2x2), each wave 4x4 of 16x16x32.
// LDS canonical layout: seg s (16B) = row (s>>2), kcol (s&3)*8; As[row*32+k].
__global__ __launch_bounds__(256) void k_gemm(const u16* __restrict__ A,
                                              const u16* __restrict__ W,
                                              u16* __restrict__ Y) {
    __shared__ u16 As[128 * 32];
    __shared__ u16 Bs[128 * 32];
    const int tid = threadIdx.x;
    const int lane = tid & 63;
    const int q = lane >> 4;       // quad 0..3
    const int l16 = lane & 15;
    const int w = tid >> 6;
    const int wm = (w >> 1) * 64, wn = (w & 1) * 64;
    const int bx = blockIdx.x, by = blockIdx.y;

    // wave w stages segments [w*128, w*128+128) via 2 calls of 64 lanes x 16B
    const int s0 = w * 128 + lane;
    const int s1 = w * 128 + 64 + lane;
    const u16* ag0 = A + (size_t)(by * 128 + (s0 >> 2)) * KK + (s0 & 3) * 8;
    const u16* ag1 = A + (size_t)(by * 128 + (s1 >> 2)) * KK + (s1 & 3) * 8;
    const u16* wg0 = W + (size_t)(bx * 128 + (s0 >> 2)) * KK + (s0 & 3) * 8;
    const u16* wg1 = W + (size_t)(bx * 128 + (s1 >> 2)) * KK + (s1 & 3) * 8;
    u16* al0 = As + w * 1024;            // wave-uniform LDS bases
    u16* al1 = As + w * 1024 + 512;
    u16* bl0 = Bs + w * 1024;
    u16* bl1 = Bs + w * 1024 + 512;

    f32x4 zero = {0.f, 0.f, 0.f, 0.f};
    f32x4 acc[4][4];
#pragma unroll
    for (int i = 0; i < 4; i++)
#pragma unroll
        for (int j = 0; j < 4; j++) acc[i][j] = zero;

    for (int k0 = 0; k0 < KK; k0 += 32) {
        __syncthreads();   // previous iter's frag reads done before overwrite
        load_lds16(ag0 + k0, al0);
        load_lds16(ag1 + k0, al1);
        load_lds16(wg0 + k0, bl0);
        load_lds16(wg1 + k0, bl1);
        __syncthreads();   // drains vmcnt(0): staged data visible
        bf16x8 af[4], bv[4];
#pragma unroll
        for (int i = 0; i < 4; i++)
            af[i] = *(const bf16x8*)&As[(wm + i * 16 + l16) * 32 + q * 8];
#pragma unroll
        for (int j = 0; j < 4; j++)
            bv[j] = *(const bf16x8*)&Bs[(wn + j * 16 + l16) * 32 + q * 8];
#pragma unroll
        for (int i = 0; i < 4; i++)
#pragma unroll
            for (int j = 0; j < 4; j++)
                acc[i][j] = __builtin_amdgcn_mfma_f32_16x16x32_bf16(
                    af[i], bv[j], acc[i][j], 0, 0, 0);
    }

    // epilogue: C/D layout col=lane&15, row=quad*4+reg
#pragma unroll
    for (int i = 0; i < 4; i++) {
#pragma unroll
        for (int rg = 0; rg < 4; rg++) {
            int row = by * 128 + wm + i * 16 + q * 4 + rg;
            u16* yp = Y + (size_t)row * NN + bx * 128 + wn + l16;
#pragma unroll
            for (int j = 0; j < 4; j++) yp[j * 16] = f2b(acc[i][j][rg]);
        }
    }
}

// ---- K2: rowwise LN(2048)+sigmoid -> FN=(f,nd) packed, R -----------------
__global__ __launch_bounds__(256) void k_lnsig(const u16* __restrict__ Y,
                                               const float* __restrict__ bg,
                                               const float* __restrict__ gg,
                                               const float* __restrict__ bt,
                                               uint32_t* __restrict__ FN,
                                               u16* __restrict__ R) {
    const int row = blockIdx.x;
    const int t = threadIdx.x;
    const u16* yr = Y + (size_t)row * 3072;
    us8 gv = *(const us8*)(yr + 1024 + t * 8);
    float z[8];
    float s = 0.f, s2 = 0.f;
#pragma unroll
    for (int k = 0; k < 8; k++) {
        z[k] = b2f(gv[k]) + bg[t * 8 + k];
        s += z[k];
        s2 += z[k] * z[k];
    }
#pragma unroll
    for (int m = 1; m < 64; m <<= 1) {
        s += __shfl_xor(s, m);
        s2 += __shfl_xor(s2, m);
    }
    __shared__ float red[8];
    if ((t & 63) == 0) { red[t >> 6] = s; red[(t >> 6) + 4] = s2; }
    __syncthreads();
    s = red[0] + red[1] + red[2] + red[3];
    s2 = red[4] + red[5] + red[6] + red[7];
    const float mu = s * (1.f / 2048.f);
    const float inv = rsqrtf(s2 * (1.f / 2048.f) - mu * mu + 1e-5f);
    float gate[8];
#pragma unroll
    for (int k = 0; k < 8; k++)
        gate[k] = sigm((z[k] - mu) * inv * gg[t * 8 + k] + bt[t * 8 + k]);
    if (t < 128) {  // f-region: pack (f, nd=(1-f)*x_tilde) into u32
        us8 xt = *(const us8*)(yr + t * 8);
        u32x8 fn;
#pragma unroll
        for (int k = 0; k < 8; k++) {
            u16 fb = f2b(gate[k]);
            u16 nb = f2b((1.f - gate[k]) * b2f(xt[k]));
            fn[k] = (uint32_t)fb | ((uint32_t)nb << 16);
        }
        *(u32x8*)(FN + (size_t)row * 1024 + t * 8) = fn;
    } else {  // r-region
        us8 ro;
#pragma unroll
        for (int k = 0; k < 8; k++) ro[k] = f2b(gate[k]);
        *(us8*)(R + (size_t)row * 1024 + (t - 128) * 8) = ro;
    }
}

// ---- K3: scan pass 1 — per-(b,h,chunk) aggregates ------------------------
__global__ __launch_bounds__(256) void k_scan1(const uint32_t* __restrict__ FN,
                                               float2* __restrict__ agg) {
    int u = blockIdx.x * 256 + threadIdx.x;
    int h = u & 1023;
    int chunk = (u >> 10) & 31;
    int b = u >> 15;
    int base = (b * 2048 + chunk * 64) * 1024 + h;
    float Fp = 1.f, Np = 0.f;
#pragma unroll 4
    for (int i = 0; i < 64; i++) {
        uint32_t v = FN[base + i * 1024];
        float f = b2f((u16)(v & 0xffffu));
        float n = b2f((u16)(v >> 16));
        Np = fmaf(f, Np, n);
        Fp *= f;
    }
    agg[(b * 1024 + h) * 32 + chunk] = make_float2(Fp, Np);
}

// ---- K4: scan over chunk aggregates -> per-chunk prefix P ----------------
__global__ __launch_bounds__(256) void k_scan2(const float2* __restrict__ agg,
                                               const float* __restrict__ c0,
                                               float* __restrict__ P) {
    int u = blockIdx.x * 256 + threadIdx.x;  // (b*1024+h), 16384 total
    float c = c0[u];
    const float2* a = agg + (size_t)u * 32;
    float* p = P + (size_t)u * 32;
#pragma unroll 4
    for (int k = 0; k < 32; k++) {
        p[k] = c;
        float2 fn = a[k];
        c = fmaf(fn.x, c, fn.y);
    }
}

// ---- K5: scan pass 2 — apply with prefix, emit all_c (bf16) + c_final ----
__global__ __launch_bounds__(256) void k_scan3(const uint32_t* __restrict__ FN,
                                               const float* __restrict__ P,
                                               u16* __restrict__ C,
                                               float* __restrict__ cfin) {
    int u = blockIdx.x * 256 + threadIdx.x;
    int h = u & 1023;
    int chunk = (u >> 10) & 31;
    int b = u >> 15;
    int base = (b * 2048 + chunk * 64) * 1024 + h;
    float c = P[(b * 1024 + h) * 32 + chunk];
#pragma unroll 4
    for (int i = 0; i < 64; i++) {
        uint32_t v = FN[base + i * 1024];
        float f = b2f((u16)(v & 0xffffu));
        float n = b2f((u16)(v >> 16));
        c = fmaf(f, c, n);
        C[base + i * 1024] = f2b(c);
    }
    if (chunk == 31) cfin[b * 1024 + h] = c;
}

// ---- K6: h = r*sigmoid(LN_h(c)) + (1-r)*x  (one wave per row) ------------
__global__ __launch_bounds__(256) void k_final(const u16* __restrict__ C,
                                               const u16* __restrict__ R,
                                               const u16* __restrict__ xb,
                                               const float* __restrict__ ga,
                                               const float* __restrict__ ba,
                                               float* __restrict__ Ho) {
    const int w = threadIdx.x >> 6, lane = threadIdx.x & 63;
    const int row = blockIdx.x * 4 + w;
    const int col = lane * 16;
    const u16* cp = C + (size_t)row * 1024 + col;
    us8 cv0 = *(const us8*)cp;
    us8 cv1 = *(const us8*)(cp + 8);
    float c[16];
    float s = 0.f, s2 = 0.f;
#pragma unroll
    for (int k = 0; k < 8; k++) { c[k] = b2f(cv0[k]); c[8 + k] = b2f(cv1[k]); }
#pragma unroll
    for (int k = 0; k < 16; k++) { s += c[k]; s2 += c[k] * c[k]; }
#pragma unroll
    for (int m = 1; m < 64; m <<= 1) {
        s += __shfl_xor(s, m);
        s2 += __shfl_xor(s2, m);
    }
    const float mu = s * (1.f / 1024.f);
    const float inv = rsqrtf(s2 * (1.f / 1024.f) - mu * mu + 1e-5f);
    const u16* rp = R + (size_t)row * 1024 + col;
    us8 rv0 = *(const us8*)rp;
    us8 rv1 = *(const us8*)(rp + 8);
    const u16* xp = xb + (size_t)row * 1024 + col;
    us8 xv0 = *(const us8*)xp;
    us8 xv1 = *(const us8*)(xp + 8);
    float ho[16];
#pragma unroll
    for (int k = 0; k < 16; k++) {
        float sg = sigm((c[k] - mu) * inv * ga[col + k] + ba[col + k]);
        float rr = b2f(k < 8 ? rv0[k] : rv1[k - 8]);
        float xx = b2f(k < 8 ? xv0[k] : xv1[k - 8]);
        ho[k] = rr * sg + (1.f - rr) * xx;
    }
    float* op = Ho + (size_t)row * 1024 + col;
    *(float4*)(op)      = *(float4*)&ho[0];
    *(float4*)(op + 4)  = *(float4*)&ho[4];
    *(float4*)(op + 8)  = *(float4*)&ho[8];
    *(float4*)(op + 12) = *(float4*)&ho[12];
}

extern "C" void kernel_launch(void* const* d_in, const int* in_sizes, int n_in,
                              void* d_out, int out_size, void* d_ws, size_t ws_size,
                              hipStream_t stream) {
    const float* x   = (const float*)d_in[0];
    const float* c0  = (const float*)d_in[1];
    const float* wlt = (const float*)d_in[2];
    const float* wg  = (const float*)d_in[3];
    const float* bg  = (const float*)d_in[4];
    const float* gg  = (const float*)d_in[5];
    const float* btg = (const float*)d_in[6];
    const float* ga  = (const float*)d_in[7];
    const float* ba  = (const float*)d_in[8];
    float* out = (float*)d_out;

    char* ws = (char*)d_ws;
    u16* xb      = (u16*)(ws);                  //  67,108,864 B
    u16* wb      = (u16*)(ws + 67108864);       //   6,291,456 B
    u16* y       = (u16*)(ws + 73400320);       // 201,326,592 B
    uint32_t* FN = (uint32_t*)(ws + 274726912); // 134,217,728 B
    u16* R       = (u16*)(ws + 408944640);      //  67,108,864 B
    float2* agg  = (float2*)(ws + 476053504);   //   4,194,304 B
    float* P     = (float*)(ws + 480247808);    //   2,097,152 B
    u16* C       = y;  // y dead after k_lnsig; reuse for all_c

    k_cvt<<<17920, 256, 0, stream>>>(x, wlt, wg, xb, wb);
    k_gemm<<<dim3(24, 256), 256, 0, stream>>>(xb, wb, y);
    k_lnsig<<<32768, 256, 0, stream>>>(y, bg, gg, btg, FN, R);
    k_scan1<<<2048, 256, 0, stream>>>(FN, agg);
    k_scan2<<<64, 256, 0, stream>>>(agg, c0, P);
    k_scan3<<<2048, 256, 0, stream>>>(FN, P, C, out + (size_t)33554432);
    k_final<<<8192, 256, 0, stream>>>(C, R, xb, ga, ba, out);
}

// Round 3
// 691.508 us; speedup vs baseline: 1.0917x; 1.0302x over previous
//
#include <hip/hip_runtime.h>
#include <stdint.h>

typedef unsigned short u16;
typedef u16 us8 __attribute__((ext_vector_type(8)));
typedef uint32_t u32x8 __attribute__((ext_vector_type(8)));
typedef __bf16 bf16x8 __attribute__((ext_vector_type(8)));
typedef float f32x4 __attribute__((ext_vector_type(4)));

#define BB 16
#define TT 2048
#define HH 1024
#define MM 32768   // B*T
#define NN 3072    // H + 2H
#define KK 1024

__device__ __forceinline__ float b2f(u16 u) {
    union { uint32_t i; float f; } v; v.i = ((uint32_t)u) << 16; return v.f;
}
__device__ __forceinline__ u16 f2b(float f) {
    union { uint32_t i; float f; } v; v.f = f;
    uint32_t r = v.i + 0x7fffu + ((v.i >> 16) & 1u);
    return (u16)(r >> 16);
}
__device__ __forceinline__ float sigm(float z) {
    return 1.f / (1.f + __expf(-z));
}
__device__ __forceinline__ void load_lds16(const u16* g, u16* l) {
    __builtin_amdgcn_global_load_lds(
        (const __attribute__((address_space(1))) void*)g,
        (__attribute__((address_space(3))) void*)l, 16, 0, 0);
}

// ---- K0: x fp32 -> bf16, [W_lt;W_g] fp32 -> bf16 (merged) ----------------
__global__ __launch_bounds__(256) void k_cvt(const float* __restrict__ x,
                                             const float* __restrict__ wlt,
                                             const float* __restrict__ wg,
                                             u16* __restrict__ xb,
                                             u16* __restrict__ wb) {
    long i = (long)(blockIdx.x * 256 + threadIdx.x) * 8;
    const float* s;
    u16* o;
    if (i < 33554432L) { s = x + i; o = xb + i; }
    else {
        long j = i - 33554432L;
        s = (j < 1048576L) ? (wlt + j) : (wg + (j - 1048576L));
        o = wb + j;
    }
    float4 a = *(const float4*)(s);
    float4 b = *(const float4*)(s + 4);
    us8 r;
    r[0] = f2b(a.x); r[1] = f2b(a.y); r[2] = f2b(a.z); r[3] = f2b(a.w);
    r[4] = f2b(b.x); r[5] = f2b(b.y); r[6] = f2b(b.z); r[7] = f2b(b.w);
    *(us8*)o = r;
}

// ---- K1: Y[32768,3072] = Xb @ Wb^T  (bf16 MFMA, m97-style staging) -------
__global__ __launch_bounds__(256) void k_gemm(const u16* __restrict__ A,
                                              const u16* __restrict__ W,
                                              u16* __restrict__ Y) {
    __shared__ u16 As[128 * 32];
    __shared__ u16 Bs[128 * 32];
    const int tid = threadIdx.x;
    const int lane = tid & 63;
    const int q = lane >> 4;       // quad 0..3
    const int l16 = lane & 15;
    const int w = tid >> 6;
    const int wm = (w >> 1) * 64, wn = (w & 1) * 64;
    const int bx = blockIdx.x, by = blockIdx.y;

    const int s0 = w * 128 + lane;
    const int s1 = w * 128 + 64 + lane;
    const u16* ag0 = A + (size_t)(by * 128 + (s0 >> 2)) * KK + (s0 & 3) * 8;
    const u16* ag1 = A + (size_t)(by * 128 + (s1 >> 2)) * KK + (s1 & 3) * 8;
    const u16* wg0 = W + (size_t)(bx * 128 + (s0 >> 2)) * KK + (s0 & 3) * 8;
    const u16* wg1 = W + (size_t)(bx * 128 + (s1 >> 2)) * KK + (s1 & 3) * 8;
    u16* al0 = As + w * 1024;
    u16* al1 = As + w * 1024 + 512;
    u16* bl0 = Bs + w * 1024;
    u16* bl1 = Bs + w * 1024 + 512;

    f32x4 zero = {0.f, 0.f, 0.f, 0.f};
    f32x4 acc[4][4];
#pragma unroll
    for (int i = 0; i < 4; i++)
#pragma unroll
        for (int j = 0; j < 4; j++) acc[i][j] = zero;

    for (int k0 = 0; k0 < KK; k0 += 32) {
        __syncthreads();
        load_lds16(ag0 + k0, al0);
        load_lds16(ag1 + k0, al1);
        load_lds16(wg0 + k0, bl0);
        load_lds16(wg1 + k0, bl1);
        __syncthreads();
        bf16x8 af[4], bv[4];
#pragma unroll
        for (int i = 0; i < 4; i++)
            af[i] = *(const bf16x8*)&As[(wm + i * 16 + l16) * 32 + q * 8];
#pragma unroll
        for (int j = 0; j < 4; j++)
            bv[j] = *(const bf16x8*)&Bs[(wn + j * 16 + l16) * 32 + q * 8];
#pragma unroll
        for (int i = 0; i < 4; i++)
#pragma unroll
            for (int j = 0; j < 4; j++)
                acc[i][j] = __builtin_amdgcn_mfma_f32_16x16x32_bf16(
                    af[i], bv[j], acc[i][j], 0, 0, 0);
    }

#pragma unroll
    for (int i = 0; i < 4; i++) {
#pragma unroll
        for (int rg = 0; rg < 4; rg++) {
            int row = by * 128 + wm + i * 16 + q * 4 + rg;
            u16* yp = Y + (size_t)row * NN + bx * 128 + wn + l16;
#pragma unroll
            for (int j = 0; j < 4; j++) yp[j * 16] = f2b(acc[i][j][rg]);
        }
    }
}

// ---- K2: rowwise LN(2048)+sigmoid -> FN=(f,nd) packed, R -----------------
__global__ __launch_bounds__(256) void k_lnsig(const u16* __restrict__ Y,
                                               const float* __restrict__ bg,
                                               const float* __restrict__ gg,
                                               const float* __restrict__ bt,
                                               uint32_t* __restrict__ FN,
                                               u16* __restrict__ R) {
    const int row = blockIdx.x;
    const int t = threadIdx.x;
    const u16* yr = Y + (size_t)row * 3072;
    us8 gv = *(const us8*)(yr + 1024 + t * 8);
    float z[8];
    float s = 0.f, s2 = 0.f;
#pragma unroll
    for (int k = 0; k < 8; k++) {
        z[k] = b2f(gv[k]) + bg[t * 8 + k];
        s += z[k];
        s2 += z[k] * z[k];
    }
#pragma unroll
    for (int m = 1; m < 64; m <<= 1) {
        s += __shfl_xor(s, m);
        s2 += __shfl_xor(s2, m);
    }
    __shared__ float red[8];
    if ((t & 63) == 0) { red[t >> 6] = s; red[(t >> 6) + 4] = s2; }
    __syncthreads();
    s = red[0] + red[1] + red[2] + red[3];
    s2 = red[4] + red[5] + red[6] + red[7];
    const float mu = s * (1.f / 2048.f);
    const float inv = rsqrtf(s2 * (1.f / 2048.f) - mu * mu + 1e-5f);
    float gate[8];
#pragma unroll
    for (int k = 0; k < 8; k++)
        gate[k] = sigm((z[k] - mu) * inv * gg[t * 8 + k] + bt[t * 8 + k]);
    if (t < 128) {
        us8 xt = *(const us8*)(yr + t * 8);
        u32x8 fn;
#pragma unroll
        for (int k = 0; k < 8; k++) {
            u16 fb = f2b(gate[k]);
            u16 nb = f2b((1.f - gate[k]) * b2f(xt[k]));
            fn[k] = (uint32_t)fb | ((uint32_t)nb << 16);
        }
        *(u32x8*)(FN + (size_t)row * 1024 + t * 8) = fn;
    } else {
        us8 ro;
#pragma unroll
        for (int k = 0; k < 8; k++) ro[k] = f2b(gate[k]);
        *(us8*)(R + (size_t)row * 1024 + (t - 128) * 8) = ro;
    }
}

// ---- K3: scan pass 1 — per-(b,h,chunk) aggregates, 2 h per thread --------
// agg layout [b][chunk][h] float2
__global__ __launch_bounds__(256) void k_scan1(const uint32_t* __restrict__ FN,
                                               float2* __restrict__ agg) {
    int u = blockIdx.x * 256 + threadIdx.x;   // 262144
    int h2 = u & 511;                          // h = 2*h2
    int chunk = (u >> 9) & 31;
    int b = u >> 14;
    size_t base = (size_t)(b * 2048 + chunk * 64) * 1024 + h2 * 2;
    float F0 = 1.f, N0 = 0.f, F1 = 1.f, N1 = 0.f;
#pragma unroll 4
    for (int i = 0; i < 64; i++) {
        uint2 v = *(const uint2*)(FN + base + (size_t)i * 1024);
        float f0 = b2f((u16)(v.x & 0xffffu)), n0 = b2f((u16)(v.x >> 16));
        float f1 = b2f((u16)(v.y & 0xffffu)), n1 = b2f((u16)(v.y >> 16));
        N0 = fmaf(f0, N0, n0); F0 *= f0;
        N1 = fmaf(f1, N1, n1); F1 *= f1;
    }
    float4 o = {F0, N0, F1, N1};
    *(float4*)&agg[(size_t)(b * 32 + chunk) * 1024 + h2 * 2] = o;
}

// ---- K4: scan over chunk aggregates -> per-chunk prefix P [b][chunk][h] --
__global__ __launch_bounds__(256) void k_scan2(const float2* __restrict__ agg,
                                               const float* __restrict__ c0,
                                               float* __restrict__ P) {
    int u = blockIdx.x * 256 + threadIdx.x;  // (b*1024+h), 16384 total
    int b = u >> 10, h = u & 1023;
    float c = c0[u];
#pragma unroll 4
    for (int k = 0; k < 32; k++) {
        size_t idx = (size_t)(b * 32 + k) * 1024 + h;
        P[idx] = c;
        float2 fn = agg[idx];
        c = fmaf(fn.x, c, fn.y);
    }
}

// ---- K5: fused scan pass 2 + LN_h + output h (no C materialization) ------
// block = (b, chunk): 512 threads x 2 h's; per-timestep block LN reduction.
__global__ __launch_bounds__(512) void k_scanout(const uint32_t* __restrict__ FN,
                                                 const float* __restrict__ P,
                                                 const u16* __restrict__ R,
                                                 const u16* __restrict__ xb,
                                                 const float* __restrict__ ga,
                                                 const float* __restrict__ ba,
                                                 float* __restrict__ out,
                                                 float* __restrict__ cfin) {
    __shared__ float2 red[2][8];
    const int t = threadIdx.x;
    const int b = blockIdx.x >> 5, chunk = blockIdx.x & 31;
    const int h = t * 2;
    const int w = t >> 6, lane = t & 63;
    float2 cp = *(const float2*)&P[(size_t)(b * 32 + chunk) * 1024 + h];
    float c0 = cp.x, c1 = cp.y;
    const float g0 = ga[h], g1 = ga[h + 1];
    const float be0 = ba[h], be1 = ba[h + 1];
    const size_t base = (size_t)(b * 2048 + chunk * 64) * 1024 + h;
#pragma unroll 2
    for (int i = 0; i < 64; i++) {
        const size_t ro = base + (size_t)i * 1024;
        uint2 fn = *(const uint2*)(FN + ro);
        uint32_t rv = *(const uint32_t*)(R + ro);   // prefetched before reduce
        uint32_t xv = *(const uint32_t*)(xb + ro);
        c0 = fmaf(b2f((u16)(fn.x & 0xffffu)), c0, b2f((u16)(fn.x >> 16)));
        c1 = fmaf(b2f((u16)(fn.y & 0xffffu)), c1, b2f((u16)(fn.y >> 16)));
        float s = c0 + c1, s2 = c0 * c0 + c1 * c1;
#pragma unroll
        for (int m = 1; m < 64; m <<= 1) {
            s += __shfl_xor(s, m);
            s2 += __shfl_xor(s2, m);
        }
        const int p = i & 1;
        if (lane == 0) red[p][w] = make_float2(s, s2);
        __syncthreads();
        s = 0.f; s2 = 0.f;
#pragma unroll
        for (int k = 0; k < 8; k++) { float2 v = red[p][k]; s += v.x; s2 += v.y; }
        const float mu = s * (1.f / 1024.f);
        const float inv = rsqrtf(s2 * (1.f / 1024.f) - mu * mu + 1e-5f);
        const float sg0 = sigm((c0 - mu) * inv * g0 + be0);
        const float sg1 = sigm((c1 - mu) * inv * g1 + be1);
        const float r0 = b2f((u16)(rv & 0xffffu)), r1 = b2f((u16)(rv >> 16));
        const float x0 = b2f((u16)(xv & 0xffffu)), x1 = b2f((u16)(xv >> 16));
        float2 ho = {r0 * sg0 + (1.f - r0) * x0, r1 * sg1 + (1.f - r1) * x1};
        *(float2*)(out + ro) = ho;
    }
    if (chunk == 31) *(float2*)(cfin + b * 1024 + h) = make_float2(c0, c1);
}

extern "C" void kernel_launch(void* const* d_in, const int* in_sizes, int n_in,
                              void* d_out, int out_size, void* d_ws, size_t ws_size,
                              hipStream_t stream) {
    const float* x   = (const float*)d_in[0];
    const float* c0  = (const float*)d_in[1];
    const float* wlt = (const float*)d_in[2];
    const float* wg  = (const float*)d_in[3];
    const float* bg  = (const float*)d_in[4];
    const float* gg  = (const float*)d_in[5];
    const float* btg = (const float*)d_in[6];
    const float* ga  = (const float*)d_in[7];
    const float* ba  = (const float*)d_in[8];
    float* out = (float*)d_out;

    char* ws = (char*)d_ws;
    u16* xb      = (u16*)(ws);                  //  67,108,864 B
    u16* wb      = (u16*)(ws + 67108864);       //   6,291,456 B
    u16* y       = (u16*)(ws + 73400320);       // 201,326,592 B
    uint32_t* FN = (uint32_t*)(ws + 274726912); // 134,217,728 B
    u16* R       = (u16*)(ws + 408944640);      //  67,108,864 B
    float2* agg  = (float2*)(ws + 476053504);   //   4,194,304 B
    float* P     = (float*)(ws + 480247808);    //   2,097,152 B

    k_cvt<<<17920, 256, 0, stream>>>(x, wlt, wg, xb, wb);
    k_gemm<<<dim3(24, 256), 256, 0, stream>>>(xb, wb, y);
    k_lnsig<<<32768, 256, 0, stream>>>(y, bg, gg, btg, FN, R);
    k_scan1<<<1024, 256, 0, stream>>>(FN, agg);
    k_scan2<<<64, 256, 0, stream>>>(agg, c0, P);
    k_scanout<<<512, 512, 0, stream>>>(FN, P, R, xb, ga, ba, out,
                                       out + (size_t)33554432);
}